// Round 3
// baseline (1909.427 us; speedup 1.0000x reference)
//
#include <hip/hip_runtime.h>
#include <cstdint>
#include <cstddef>

#define B_   16
#define D_   192
#define TY   2048
#define TX   512
#define NEG_INF_F (-1e9f)

#define CHUNK 10
#define RING  3

// ======================= K1: nc14[b,x] = nc1 + nc4 =======================
__global__ __launch_bounds__(256)
void nc14_kernel(const float* __restrict__ m_p,
                 const float* __restrict__ logs_p,
                 float* __restrict__ nc14) {
    int gid = blockIdx.x * 256 + threadIdx.x;       // 0..8191  (B*TX)
    int b = gid >> 9;
    int x = gid & 511;
    const float c = -0.9189385332046727f;           // -0.5*log(2*pi)
    const float* lp = logs_p + (size_t)b * D_ * TX + x;
    const float* mp = m_p    + (size_t)b * D_ * TX + x;
    float acc1 = 0.f, acc2 = 0.f;
    for (int d = 0; d < D_; ++d) {
        float l = lp[(size_t)d * TX];
        float m = mp[(size_t)d * TX];
        float s = __expf(-2.f * l);
        acc1 += c - l;
        acc2 += m * m * s;
    }
    nc14[gid] = acc1 - 0.5f * acc2;
}

// ======================= K2: fp32 GEMM for neg_cent =======================
// C[b,y,x] = nc14[b,x] + sum_d( (-0.5 z^2)[d,y]*s[d,x] + z[d,y]*(m*s)[d,x] )
#define BM 128
#define BN 128
#define BK 16

__global__ __launch_bounds__(256, 2)
void gemm_kernel(const float* __restrict__ z_p,
                 const float* __restrict__ m_p,
                 const float* __restrict__ logs_p,
                 const float* __restrict__ nc14,
                 float* __restrict__ out) {
    __shared__ float a_z [BK][BM];
    __shared__ float a_z2[BK][BM];
    __shared__ float sb_s [BK][BN];
    __shared__ float sb_ms[BK][BN];

    const int b  = blockIdx.z;
    const int m0 = blockIdx.y * BM;
    const int n0 = blockIdx.x * BN;
    const int tid = threadIdx.x;
    const int tx = tid & 15;      // 16 col-groups of 8
    const int ty = tid >> 4;      // 16 row-groups of 8

    const float* zb = z_p    + (size_t)b * D_ * TY;
    const float* mb = m_p    + (size_t)b * D_ * TX;
    const float* lb = logs_p + (size_t)b * D_ * TX;

    float acc[8][8];
    #pragma unroll
    for (int i = 0; i < 8; ++i)
        #pragma unroll
        for (int j = 0; j < 8; ++j) acc[i][j] = 0.f;

    for (int k0 = 0; k0 < D_; k0 += BK) {
        // ---- stage A tile: BK x 128 (z and -0.5 z^2): 512 float4, 2/thread
        #pragma unroll
        for (int q = 0; q < 2; ++q) {
            int idx = tid * 2 + q;            // 0..511
            int kk = idx >> 5;                // 16 rows
            int yy = (idx & 31) * 4;          // 128 cols
            float4 v = *(const float4*)(zb + (size_t)(k0 + kk) * TY + m0 + yy);
            *(float4*)&a_z[kk][yy] = v;
            float4 w;
            w.x = -0.5f * v.x * v.x; w.y = -0.5f * v.y * v.y;
            w.z = -0.5f * v.z * v.z; w.w = -0.5f * v.w * v.w;
            *(float4*)&a_z2[kk][yy] = w;
        }
        // ---- stage B tile: BK x 128 (s and m*s): 512 float4 each, 2/thread
        #pragma unroll
        for (int q = 0; q < 2; ++q) {
            int idx = tid * 2 + q;
            int kk = idx >> 5;
            int xx = (idx & 31) * 4;
            float4 lg = *(const float4*)(lb + (size_t)(k0 + kk) * TX + n0 + xx);
            float4 mm = *(const float4*)(mb + (size_t)(k0 + kk) * TX + n0 + xx);
            float4 s;
            s.x = __expf(-2.f * lg.x); s.y = __expf(-2.f * lg.y);
            s.z = __expf(-2.f * lg.z); s.w = __expf(-2.f * lg.w);
            *(float4*)&sb_s[kk][xx] = s;
            float4 ms;
            ms.x = mm.x * s.x; ms.y = mm.y * s.y;
            ms.z = mm.z * s.z; ms.w = mm.w * s.w;
            *(float4*)&sb_ms[kk][xx] = ms;
        }
        __syncthreads();
        #pragma unroll
        for (int kk = 0; kk < BK; ++kk) {
            float az[8], a2[8], bs[8], bm[8];
            *(float4*)&az[0] = *(const float4*)&a_z [kk][ty * 8];
            *(float4*)&az[4] = *(const float4*)&a_z [kk][ty * 8 + 4];
            *(float4*)&a2[0] = *(const float4*)&a_z2[kk][ty * 8];
            *(float4*)&a2[4] = *(const float4*)&a_z2[kk][ty * 8 + 4];
            *(float4*)&bs[0] = *(const float4*)&sb_s [kk][tx * 8];
            *(float4*)&bs[4] = *(const float4*)&sb_s [kk][tx * 8 + 4];
            *(float4*)&bm[0] = *(const float4*)&sb_ms[kk][tx * 8];
            *(float4*)&bm[4] = *(const float4*)&sb_ms[kk][tx * 8 + 4];
            #pragma unroll
            for (int i = 0; i < 8; ++i)
                #pragma unroll
                for (int j = 0; j < 8; ++j)
                    acc[i][j] += a2[i] * bs[j] + az[i] * bm[j];
        }
        __syncthreads();
    }
    // ---- epilogue: += nc14, store
    float4 c40 = *(const float4*)(nc14 + b * TX + n0 + tx * 8);
    float4 c41 = *(const float4*)(nc14 + b * TX + n0 + tx * 8 + 4);
    float* ob = out + (size_t)b * TY * TX + (size_t)m0 * TX + n0 + tx * 8;
    #pragma unroll
    for (int i = 0; i < 8; ++i) {
        float4 r0, r1;
        r0.x = acc[i][0] + c40.x; r0.y = acc[i][1] + c40.y;
        r0.z = acc[i][2] + c40.z; r0.w = acc[i][3] + c40.w;
        r1.x = acc[i][4] + c41.x; r1.y = acc[i][5] + c41.y;
        r1.z = acc[i][6] + c41.z; r1.w = acc[i][7] + c41.w;
        float* p = ob + (size_t)(ty * 8 + i) * TX;
        *(float4*)p       = r0;
        *(float4*)(p + 4) = r1;
    }
}

// ======================= K3: DP, producer-consumer =======================
// 4 waves/block, 1 block/batch. Wave 0 computes the serial DP; waves 1-3
// stage neg_cent rows into an LDS ring (3 x 10 rows x 2KB = 60KB) with
// register double-buffering. Flag-based sync (no __syncthreads) so the
// compute wave never drains vmcnt. LDS row layout swizzled: floats
// [x: x%8<4 packed by lane][x: x%8>=4 packed by lane] so both ds_write_b128
// and ds_read_b128 are stride-16B (conflict-free).
template<int R0, int NR>
__device__ __forceinline__ void loader_fn(const float* __restrict__ nc,
                                          float* rows, int* filled_slot,
                                          int* consumed, int NC, int lane) {
    float4 A[NR][2], Bv[NR][2];
    auto issue = [&](float4 (&R)[NR][2], int c) {
        #pragma unroll
        for (int k = 0; k < NR; ++k) {
            int y = c * CHUNK + R0 + k;
            if (y > TY - 1) y = TY - 1;
            const float* p = nc + (size_t)y * TX + lane * 8;
            R[k][0] = *(const float4*)p;
            R[k][1] = *(const float4*)(p + 4);
        }
    };
    auto wr = [&](float4 (&R)[NR][2], int c) {
        float* base = rows + (size_t)(c % RING) * (CHUNK * TX);
        #pragma unroll
        for (int k = 0; k < NR; ++k) {
            float* rb = base + (R0 + k) * TX;
            *(float4*)(rb + 4 * lane)       = R[k][0];
            *(float4*)(rb + 256 + 4 * lane) = R[k][1];
        }
    };
    auto waitc = [&](int th) {
        if (th <= 0) return;
        while (__hip_atomic_load(consumed, __ATOMIC_ACQUIRE,
                                 __HIP_MEMORY_SCOPE_WORKGROUP) < th)
            __builtin_amdgcn_s_sleep(1);
    };
    auto pub = [&](int v) {
        if (lane == 0)
            __hip_atomic_store(filled_slot, v, __ATOMIC_RELEASE,
                               __HIP_MEMORY_SCOPE_WORKGROUP);
    };
    issue(A, 0);
    if (NC > 1) issue(Bv, 1);
    for (int c = 0; c < NC; c += 2) {
        waitc(c - (RING - 1));
        wr(A, c);
        pub(c + 1);
        if (c + 2 < NC) issue(A, c + 2);
        if (c + 1 < NC) {
            waitc(c + 1 - (RING - 1));
            wr(Bv, c + 1);
            pub(c + 2);
            if (c + 3 < NC) issue(Bv, c + 3);
        }
    }
}

__global__ __launch_bounds__(256, 1)
void dp_kernel(float* __restrict__ out,
               const int* __restrict__ t_xs,
               const int* __restrict__ t_ys,
               int* __restrict__ cumE) {
    const size_t PLANE = (size_t)TY * TX;
    const size_t OFF1  = (size_t)B_ * PLANE;
    const size_t OFF2  = 2 * OFF1;

    __shared__ float rows_lds[RING * CHUNK * TX];   // 60 KB
    __shared__ int   filled[3];
    __shared__ int   consumed_v;

    const int b    = blockIdx.x;
    const int tid  = threadIdx.x;
    const int wid  = tid >> 6;
    const int lane = tid & 63;
    const int t_x  = t_xs[b];
    const int t_y  = t_ys[b];
    const int NC   = (t_y + CHUNK - 1) / CHUNK;

    const float* nc   = out + (size_t)b * PLANE;
    float*       attn = out + OFF1 + (size_t)b * PLANE;
    float*       logw = out + OFF2 + (size_t)b * TX;
    unsigned char* bitsb = (unsigned char*)attn;

    if (tid < 3) filled[tid] = 0;
    if (tid == 3) consumed_v = 0;
    __syncthreads();   // only barrier: all 4 waves alive here

    if (wid == 1) { loader_fn<0, 4>(nc, rows_lds, &filled[0], &consumed_v, NC, lane); return; }
    if (wid == 2) { loader_fn<4, 3>(nc, rows_lds, &filled[1], &consumed_v, NC, lane); return; }
    if (wid == 3) { loader_fn<7, 3>(nc, rows_lds, &filled[2], &consumed_v, NC, lane); return; }

    // ================= compute wave =================
    float cum[8];
    #pragma unroll
    for (int j = 0; j < 8; ++j) cum[j] = NEG_INF_F;

    auto step = [&](int yy, float4 va, float4 vb) {
        float up  = __shfl_up(cum[7], 1, 64);
        float sh0 = (lane == 0) ? NEG_INF_F : up;
        unsigned bits = (cum[0] < sh0) ? 1u : 0u;
        #pragma unroll
        for (int j = 1; j < 8; ++j)
            bits |= (cum[j] < cum[j - 1]) ? (1u << j) : 0u;
        float v[8] = {va.x, va.y, va.z, va.w, vb.x, vb.y, vb.z, vb.w};
        float c0 = v[0] + fmaxf(cum[0], sh0);
        #pragma unroll
        for (int j = 7; j >= 1; --j)          // descending: uses old cum[j-1]
            cum[j] = v[j] + fmaxf(cum[j], cum[j - 1]);
        cum[0] = c0;
        bitsb[(size_t)yy * 2048 + lane] = (unsigned char)bits;
    };

    auto poll = [&](int target) {
        for (;;) {
            int f0 = __hip_atomic_load(&filled[0], __ATOMIC_ACQUIRE, __HIP_MEMORY_SCOPE_WORKGROUP);
            int f1 = __hip_atomic_load(&filled[1], __ATOMIC_ACQUIRE, __HIP_MEMORY_SCOPE_WORKGROUP);
            int f2 = __hip_atomic_load(&filled[2], __ATOMIC_ACQUIRE, __HIP_MEMORY_SCOPE_WORKGROUP);
            if (f0 >= target && f1 >= target && f2 >= target) break;
        }
    };

#define RD1(r) (*(const float4*)(base + (r) * TX + 4 * lane))
#define RD2(r) (*(const float4*)(base + (r) * TX + 256 + 4 * lane))
#define ROW(r, SA, SB)                                                      \
    do {                                                                    \
        int y = c * CHUNK + (r);                                            \
        if (y == 0) { cum[0] = (lane == 0) ? SA.x : NEG_INF_F; }            \
        else if (y < t_y) step(y, SA, SB);                                  \
    } while (0)

    for (int c = 0; c < NC; ++c) {
        poll(c + 1);
        const float* base = rows_lds + (size_t)(c % RING) * (CHUNK * TX);
        float4 s0a = RD1(0), s0b = RD2(0);
        float4 s1a = RD1(1), s1b = RD2(1);
        float4 s2a = RD1(2), s2b = RD2(2);
        float4 s3a = RD1(3), s3b = RD2(3);
        ROW(0, s0a, s0b); s0a = RD1(4); s0b = RD2(4);
        ROW(1, s1a, s1b); s1a = RD1(5); s1b = RD2(5);
        ROW(2, s2a, s2b); s2a = RD1(6); s2b = RD2(6);
        ROW(3, s3a, s3b); s3a = RD1(7); s3b = RD2(7);
        ROW(4, s0a, s0b); s0a = RD1(8); s0b = RD2(8);
        ROW(5, s1a, s1b); s1a = RD1(9); s1b = RD2(9);
        ROW(6, s2a, s2b);
        ROW(7, s3a, s3b);
        ROW(8, s0a, s0b);
        ROW(9, s1a, s1b);
        if (lane == 0)
            __hip_atomic_store(&consumed_v, c + 1, __ATOMIC_RELAXED,
                               __HIP_MEMORY_SCOPE_WORKGROUP);
    }
#undef RD1
#undef RD2
#undef ROW

    // make forward bit-stores visible to backtrack loads (same wave)
    __builtin_amdgcn_s_waitcnt(0);

    // ---------------- backtrack (durations only) ----------------
    int* w_lds = (int*)rows_lds;          // rows ring is dead now
    #pragma unroll
    for (int j = 0; j < 8; ++j) w_lds[lane * 8 + j] = 0;

    int idx  = t_x - 1;
    int yhi  = t_y - 1;
    int ytop = t_y - 1;
    while (ytop >= 0) {
        int cnt = (ytop >= 31) ? 32 : (ytop + 1);
        int wh  = idx >> 5;
        int wlo = (wh > 0) ? wh - 1 : 0;
        unsigned vlo = 0u, vhi = 0u;
        if (lane < cnt) {
            const unsigned* rp = (const unsigned*)attn + (size_t)(ytop - lane) * TX;
            vlo = rp[wlo];
            vhi = rp[wh];
        }
        int base = wlo * 32;
        auto body = [&](int i) {
            int yy = ytop - i;
            unsigned lo = __shfl(vlo, i, 64);
            unsigned hi = __shfl(vhi, i, 64);
            unsigned long long V = ((unsigned long long)hi << 32) | lo;
            int pos   = idx - base;
            int bit   = (int)((V >> pos) & 1ull);
            int force = (idx == yy) ? 1 : 0;
            int move  = (force | bit) & ((idx > 0) ? 1 : 0) & ((yy > 0) ? 1 : 0);
            if (move) {
                if (lane == 0) w_lds[idx] = yhi - yy + 1;
                yhi = yy - 1;
                idx -= 1;
            }
        };
        if (cnt == 32) {
            #pragma unroll
            for (int i = 0; i < 32; ++i) body(i);
        } else {
            for (int i = 0; i < cnt; ++i) body(i);
        }
        ytop -= cnt;
    }
    if (lane == 0) w_lds[idx] = yhi + 1;   // phoneme holding row 0

    // ---------------- logw + prefix-sum -> cumE ----------------
    int v[8];
    int run = 0;
    #pragma unroll
    for (int j = 0; j < 8; ++j) {
        int wv = w_lds[lane * 8 + j];
        run += wv;
        v[j] = run;                   // inclusive within lane
    }
    int off = run;
    #pragma unroll
    for (int d = 1; d < 64; d <<= 1) {
        int t = __shfl_up(off, d, 64);
        if (lane >= d) off += t;
    }
    int excl = off - run;             // exclusive across lanes
    #pragma unroll
    for (int j = 0; j < 8; ++j) {
        int x = lane * 8 + j;
        cumE[b * TX + x] = v[j] + excl;
        int wv = w_lds[x];
        logw[x] = (x < t_x) ? logf((float)wv + 1e-6f) : 0.f;
    }
}

// ======================= K4: attn one-hot fill =======================
__global__ __launch_bounds__(256)
void attn_fill_kernel(const int* __restrict__ cumE,
                      float* __restrict__ out) {
    const size_t PLANE = (size_t)TY * TX;
    const size_t OFF1  = (size_t)B_ * PLANE;
    __shared__ int cs[TX + 1];
    const int b  = blockIdx.y;
    const int y0 = blockIdx.x * 4;
    const int t  = threadIdx.x;
    if (t == 0) cs[0] = 0;
    cs[1 + t]       = cumE[b * TX + t];
    cs[1 + 256 + t] = cumE[b * TX + 256 + t];
    __syncthreads();
    const int y  = y0 + (t >> 6);
    const int x0 = (t & 63) * 8;
    float r[8];
    #pragma unroll
    for (int j = 0; j < 8; ++j)
        r[j] = (cs[x0 + j] <= y && y < cs[x0 + j + 1]) ? 1.f : 0.f;
    float* p = out + OFF1 + (size_t)b * PLANE + (size_t)y * TX + x0;
    *(float4*)p       = *(float4*)&r[0];
    *(float4*)(p + 4) = *(float4*)&r[4];
}

// ======================= launch =======================
extern "C" void kernel_launch(void* const* d_in, const int* in_sizes, int n_in,
                              void* d_out, int out_size, void* d_ws, size_t ws_size,
                              hipStream_t stream) {
    const float* z_p    = (const float*)d_in[0];
    const float* m_p    = (const float*)d_in[1];
    const float* logs_p = (const float*)d_in[2];
    const int* ph_len   = (const int*)d_in[3];
    const int* mel_len  = (const int*)d_in[4];
    float* out  = (float*)d_out;
    float* nc14 = (float*)d_ws;          // 16*512 floats = 32 KB
    int*   cumE = (int*)d_ws;            // reuses nc14's space (dead after gemm)

    nc14_kernel<<<(B_ * TX) / 256, 256, 0, stream>>>(m_p, logs_p, nc14);
    gemm_kernel<<<dim3(TX / BN, TY / BM, B_), 256, 0, stream>>>(z_p, m_p, logs_p, nc14, out);
    dp_kernel<<<B_, 256, 0, stream>>>(out, ph_len, mel_len, cumE);
    attn_fill_kernel<<<dim3(TY / 4, B_), 256, 0, stream>>>(cumE, out);
}

// Round 4
// 1037.356 us; speedup vs baseline: 1.8407x; 1.8407x over previous
//
#include <hip/hip_runtime.h>
#include <cstdint>
#include <cstddef>

#define B_   16
#define D_   192
#define TY   2048
#define TX   512
#define NEG_INF_F (-1e9f)

#define CHUNK 10
#define RING  3

// s_waitcnt imm (gfx9): vmcnt[3:0]=bits3:0, expcnt=bits6:4, lgkmcnt=bits11:8,
// vmcnt[5:4]=bits15:14. Wait on vmcnt only (exp/lgkm = max).
#define WAITVM(N) __builtin_amdgcn_s_waitcnt(((N) & 15) | (7 << 4) | (15 << 8) | (((N) >> 4) << 14))

__device__ __forceinline__ void gload_lds16(const float* g, float* l) {
    __builtin_amdgcn_global_load_lds(
        (const __attribute__((address_space(1))) void*)g,
        (__attribute__((address_space(3))) void*)l, 16, 0, 0);
}

// ======================= K1: nc14[b,x] = nc1 + nc4 =======================
__global__ __launch_bounds__(256)
void nc14_kernel(const float* __restrict__ m_p,
                 const float* __restrict__ logs_p,
                 float* __restrict__ nc14) {
    int gid = blockIdx.x * 256 + threadIdx.x;       // 0..8191  (B*TX)
    int b = gid >> 9;
    int x = gid & 511;
    const float c = -0.9189385332046727f;           // -0.5*log(2*pi)
    const float* lp = logs_p + (size_t)b * D_ * TX + x;
    const float* mp = m_p    + (size_t)b * D_ * TX + x;
    float acc1 = 0.f, acc2 = 0.f;
    for (int d = 0; d < D_; ++d) {
        float l = lp[(size_t)d * TX];
        float m = mp[(size_t)d * TX];
        float s = __expf(-2.f * l);
        acc1 += c - l;
        acc2 += m * m * s;
    }
    nc14[gid] = acc1 - 0.5f * acc2;
}

// ======================= K2: fp32 GEMM for neg_cent =======================
// C[b,y,x] = nc14[b,x] + sum_d( (-0.5 z^2)[d,y]*s[d,x] + z[d,y]*(m*s)[d,x] )
// 512 threads, 128x128 tile, 8x4 micro-tile -> ~100 VGPR (R3's (256,2) clamp
// at 128 VGPR spilled 3.16 GB of scratch; NEVER clamp below need).
#define BM 128
#define BN 128
#define BK 16

__global__ __launch_bounds__(512)
void gemm_kernel(const float* __restrict__ z_p,
                 const float* __restrict__ m_p,
                 const float* __restrict__ logs_p,
                 const float* __restrict__ nc14,
                 float* __restrict__ out) {
    __shared__ float a_z [BK][BM];
    __shared__ float a_z2[BK][BM];
    __shared__ float sb_s [BK][BN];
    __shared__ float sb_ms[BK][BN];   // 32 KB total

    const int b  = blockIdx.z;
    const int m0 = blockIdx.y * BM;
    const int n0 = blockIdx.x * BN;
    const int tid = threadIdx.x;
    const int tx = tid & 31;      // 32 col-groups of 4
    const int ty = tid >> 5;      // 16 row-groups of 8

    const int skk = tid >> 5;          // staging row 0..15
    const int sy  = (tid & 31) * 4;    // staging col 0..124

    const float* zb = z_p    + (size_t)b * D_ * TY;
    const float* mb = m_p    + (size_t)b * D_ * TX;
    const float* lb = logs_p + (size_t)b * D_ * TX;

    float acc[8][4];
    #pragma unroll
    for (int i = 0; i < 8; ++i)
        #pragma unroll
        for (int j = 0; j < 4; ++j) acc[i][j] = 0.f;

    float4 va, vlg, vmm;
    auto ld = [&](int k0) {
        va  = *(const float4*)(zb + (size_t)(k0 + skk) * TY + m0 + sy);
        vlg = *(const float4*)(lb + (size_t)(k0 + skk) * TX + n0 + sy);
        vmm = *(const float4*)(mb + (size_t)(k0 + skk) * TX + n0 + sy);
    };
    auto st = [&]() {
        *(float4*)&a_z[skk][sy] = va;
        float4 w;
        w.x = -0.5f * va.x * va.x; w.y = -0.5f * va.y * va.y;
        w.z = -0.5f * va.z * va.z; w.w = -0.5f * va.w * va.w;
        *(float4*)&a_z2[skk][sy] = w;
        float4 s;
        s.x = __expf(-2.f * vlg.x); s.y = __expf(-2.f * vlg.y);
        s.z = __expf(-2.f * vlg.z); s.w = __expf(-2.f * vlg.w);
        *(float4*)&sb_s[skk][sy] = s;
        float4 ms;
        ms.x = vmm.x * s.x; ms.y = vmm.y * s.y;
        ms.z = vmm.z * s.z; ms.w = vmm.w * s.w;
        *(float4*)&sb_ms[skk][sy] = ms;
    };

    ld(0);
    for (int k0 = 0; k0 < D_; k0 += BK) {
        st();
        __syncthreads();
        if (k0 + BK < D_) ld(k0 + BK);   // prefetch next tile during compute
        #pragma unroll
        for (int kk = 0; kk < BK; ++kk) {
            float az[8], a2[8], bs[4], bm[4];
            *(float4*)&az[0] = *(const float4*)&a_z [kk][ty * 8];
            *(float4*)&az[4] = *(const float4*)&a_z [kk][ty * 8 + 4];
            *(float4*)&a2[0] = *(const float4*)&a_z2[kk][ty * 8];
            *(float4*)&a2[4] = *(const float4*)&a_z2[kk][ty * 8 + 4];
            *(float4*)&bs[0] = *(const float4*)&sb_s [kk][tx * 4];
            *(float4*)&bm[0] = *(const float4*)&sb_ms[kk][tx * 4];
            #pragma unroll
            for (int i = 0; i < 8; ++i)
                #pragma unroll
                for (int j = 0; j < 4; ++j)
                    acc[i][j] += a2[i] * bs[j] + az[i] * bm[j];
        }
        __syncthreads();
    }
    const float4 c4 = *(const float4*)(nc14 + b * TX + n0 + tx * 4);
    float* ob = out + (size_t)b * TY * TX + (size_t)m0 * TX + n0 + tx * 4;
    #pragma unroll
    for (int i = 0; i < 8; ++i) {
        float4 r;
        r.x = acc[i][0] + c4.x; r.y = acc[i][1] + c4.y;
        r.z = acc[i][2] + c4.z; r.w = acc[i][3] + c4.w;
        *(float4*)(ob + (size_t)(ty * 8 + i) * TX) = r;
    }
}

// ======================= K3: DP, single-wave async pipeline =======================
// One 64-lane wave per batch. The wave itself issues global_load_lds (width 16,
// direct HBM->LDS, no VGPR round trip) for chunk c+2 into a 3-slot LDS ring,
// then gates on s_waitcnt vmcnt(N). N is exact because vmcnt retires in order
// and the queue is deterministic: 20 loads/chunk + exactly 10 bit-stores/chunk
// (row 0 stores a dummy byte to keep the count uniform).
// Per-lane global addresses are swizzled so LDS layout = [x%8<4 half][x%8>=4
// half], making both the DMA and the ds_read_b128 conflict-free.
__global__ __launch_bounds__(64, 1)
void dp_kernel(float* __restrict__ out,
               const int* __restrict__ t_xs,
               const int* __restrict__ t_ys,
               int* __restrict__ cumE) {
    const size_t PLANE = (size_t)TY * TX;
    const size_t OFF1  = (size_t)B_ * PLANE;
    const size_t OFF2  = 2 * OFF1;

    __shared__ float rows_lds[RING * CHUNK * TX];   // 60 KB
    __shared__ int   w_lds[TX];                     // 2 KB

    const int b    = blockIdx.x;
    const int lane = threadIdx.x;
    const int t_x  = t_xs[b];
    const int t_y  = t_ys[b];
    const int tym1 = t_y - 1;
    const int NC   = (t_y + CHUNK - 1) / CHUNK;

    const float* nc   = out + (size_t)b * PLANE;
    float*       attn = out + OFF1 + (size_t)b * PLANE;
    float*       logw = out + OFF2 + (size_t)b * TX;
    unsigned char* bitsb = (unsigned char*)attn;

    #pragma unroll
    for (int j = 0; j < 8; ++j) w_lds[lane * 8 + j] = 0;

    auto issue_chunk = [&](int c) {
        const int slot = c % RING;
        #pragma unroll
        for (int r = 0; r < CHUNK; ++r) {
            int y = c * CHUNK + r;
            if (y > tym1) y = tym1;
            const float* gp = nc + (size_t)y * TX + 8 * lane;   // lane-swizzled
            float* lp = rows_lds + (size_t)(slot * CHUNK + r) * TX;
            gload_lds16(gp,     lp);        // lanes land at lp + 16B*lane
            gload_lds16(gp + 4, lp + 256);
        }
    };

    // ---------------- forward ----------------
    float cum[8];
    #pragma unroll
    for (int j = 0; j < 8; ++j) cum[j] = NEG_INF_F;

    auto step = [&](int yy, float4 va, float4 vb) {
        float up  = __shfl_up(cum[7], 1, 64);
        float sh0 = (lane == 0) ? NEG_INF_F : up;
        unsigned bits = (cum[0] < sh0) ? 1u : 0u;
        #pragma unroll
        for (int j = 1; j < 8; ++j)
            bits |= (cum[j] < cum[j - 1]) ? (1u << j) : 0u;
        float v[8] = {va.x, va.y, va.z, va.w, vb.x, vb.y, vb.z, vb.w};
        float c0 = v[0] + fmaxf(cum[0], sh0);
        #pragma unroll
        for (int j = 7; j >= 1; --j)          // descending: uses old cum[j-1]
            cum[j] = v[j] + fmaxf(cum[j], cum[j - 1]);
        cum[0] = c0;
        bitsb[(size_t)yy * 2048 + lane] = (unsigned char)bits;
    };

    issue_chunk(0);
    if (NC > 1) issue_chunk(1);

#define RD1(r) (*(const float4*)(base + (r) * TX + 4 * lane))
#define RD2(r) (*(const float4*)(base + (r) * TX + 256 + 4 * lane))
#define ROW(r, SA, SB)                                                      \
    do {                                                                    \
        int y = c * CHUNK + (r);                                            \
        if (y == 0) { cum[0] = (lane == 0) ? SA.x : NEG_INF_F;              \
                      bitsb[lane] = 0; /* dummy: uniform store count */ }   \
        else if (y < t_y) step(y, SA, SB);                                  \
    } while (0)

    for (int c = 0; c < NC; ++c) {
        bool full = (c + 2 < NC);
        if (full) issue_chunk(c + 2);
        // queue (oldest first): L(c)20, L(c+1)20, [S(c-1)10 if c>0], L(c+2)20
        if (c == 0)      { WAITVM(40); }
        else if (full)   { WAITVM(50); }
        else             { WAITVM(0);  }
        __asm__ volatile("" ::: "memory");
        const float* base = rows_lds + (size_t)(c % RING) * (CHUNK * TX);
        float4 s0a = RD1(0), s0b = RD2(0);
        float4 s1a = RD1(1), s1b = RD2(1);
        float4 s2a = RD1(2), s2b = RD2(2);
        float4 s3a = RD1(3), s3b = RD2(3);
        ROW(0, s0a, s0b); s0a = RD1(4); s0b = RD2(4);
        ROW(1, s1a, s1b); s1a = RD1(5); s1b = RD2(5);
        ROW(2, s2a, s2b); s2a = RD1(6); s2b = RD2(6);
        ROW(3, s3a, s3b); s3a = RD1(7); s3b = RD2(7);
        ROW(4, s0a, s0b); s0a = RD1(8); s0b = RD2(8);
        ROW(5, s1a, s1b); s1a = RD1(9); s1b = RD2(9);
        ROW(6, s2a, s2b);
        ROW(7, s3a, s3b);
        ROW(8, s0a, s0b);
        ROW(9, s1a, s1b);
    }
#undef RD1
#undef RD2
#undef ROW

    // drain bit-stores before reading them back
    __builtin_amdgcn_s_waitcnt(0);
    __asm__ volatile("" ::: "memory");

    // ---------------- backtrack (durations only) ----------------
    int idx  = t_x - 1;
    int yhi  = t_y - 1;
    int ytop = t_y - 1;
    while (ytop >= 0) {
        int cnt = (ytop >= 31) ? 32 : (ytop + 1);
        int wh  = idx >> 5;
        int wlo = (wh > 0) ? wh - 1 : 0;
        unsigned vlo = 0u, vhi = 0u;
        if (lane < cnt) {
            const unsigned* rp = (const unsigned*)attn + (size_t)(ytop - lane) * TX;
            vlo = rp[wlo];
            vhi = rp[wh];
        }
        int base = wlo * 32;
        auto body = [&](int i) {
            int yy = ytop - i;
            unsigned lo = __shfl(vlo, i, 64);
            unsigned hi = __shfl(vhi, i, 64);
            unsigned long long V = ((unsigned long long)hi << 32) | lo;
            int pos   = idx - base;
            int bit   = (int)((V >> pos) & 1ull);
            int force = (idx == yy) ? 1 : 0;
            int move  = (force | bit) & ((idx > 0) ? 1 : 0) & ((yy > 0) ? 1 : 0);
            if (move) {
                if (lane == 0) w_lds[idx] = yhi - yy + 1;
                yhi = yy - 1;
                idx -= 1;
            }
        };
        if (cnt == 32) {
            #pragma unroll
            for (int i = 0; i < 32; ++i) body(i);
        } else {
            for (int i = 0; i < cnt; ++i) body(i);
        }
        ytop -= cnt;
    }
    if (lane == 0) w_lds[idx] = yhi + 1;   // phoneme holding row 0

    // ---------------- logw + prefix-sum -> cumE ----------------
    int v[8];
    int run = 0;
    #pragma unroll
    for (int j = 0; j < 8; ++j) {
        int wv = w_lds[lane * 8 + j];
        run += wv;
        v[j] = run;                   // inclusive within lane
    }
    int off = run;
    #pragma unroll
    for (int d = 1; d < 64; d <<= 1) {
        int t = __shfl_up(off, d, 64);
        if (lane >= d) off += t;
    }
    int excl = off - run;             // exclusive across lanes
    #pragma unroll
    for (int j = 0; j < 8; ++j) {
        int x = lane * 8 + j;
        cumE[b * TX + x] = v[j] + excl;
        int wv = w_lds[x];
        logw[x] = (x < t_x) ? logf((float)wv + 1e-6f) : 0.f;
    }
}

// ======================= K4: attn one-hot fill =======================
__global__ __launch_bounds__(256)
void attn_fill_kernel(const int* __restrict__ cumE,
                      float* __restrict__ out) {
    const size_t PLANE = (size_t)TY * TX;
    const size_t OFF1  = (size_t)B_ * PLANE;
    __shared__ int cs[TX + 1];
    const int b  = blockIdx.y;
    const int y0 = blockIdx.x * 4;
    const int t  = threadIdx.x;
    if (t == 0) cs[0] = 0;
    cs[1 + t]       = cumE[b * TX + t];
    cs[1 + 256 + t] = cumE[b * TX + 256 + t];
    __syncthreads();
    const int y  = y0 + (t >> 6);
    const int x0 = (t & 63) * 8;
    float r[8];
    #pragma unroll
    for (int j = 0; j < 8; ++j)
        r[j] = (cs[x0 + j] <= y && y < cs[x0 + j + 1]) ? 1.f : 0.f;
    float* p = out + OFF1 + (size_t)b * PLANE + (size_t)y * TX + x0;
    *(float4*)p       = *(float4*)&r[0];
    *(float4*)(p + 4) = *(float4*)&r[4];
}

// ======================= launch =======================
extern "C" void kernel_launch(void* const* d_in, const int* in_sizes, int n_in,
                              void* d_out, int out_size, void* d_ws, size_t ws_size,
                              hipStream_t stream) {
    const float* z_p    = (const float*)d_in[0];
    const float* m_p    = (const float*)d_in[1];
    const float* logs_p = (const float*)d_in[2];
    const int* ph_len   = (const int*)d_in[3];
    const int* mel_len  = (const int*)d_in[4];
    float* out  = (float*)d_out;
    float* nc14 = (float*)d_ws;          // 16*512 floats = 32 KB
    int*   cumE = (int*)d_ws;            // reuses nc14's space (dead after gemm)

    nc14_kernel<<<(B_ * TX) / 256, 256, 0, stream>>>(m_p, logs_p, nc14);
    gemm_kernel<<<dim3(TX / BN, TY / BM, B_), 512, 0, stream>>>(z_p, m_p, logs_p, nc14, out);
    dp_kernel<<<B_, 64, 0, stream>>>(out, ph_len, mel_len, cumE);
    attn_fill_kernel<<<dim3(TY / 4, B_), 256, 0, stream>>>(cumE, out);
}

// Round 5
// 928.342 us; speedup vs baseline: 2.0568x; 1.1174x over previous
//
#include <hip/hip_runtime.h>
#include <cstdint>
#include <cstddef>

#define B_   16
#define D_   192
#define TY   2048
#define TX   512
#define NEG_INF_F (-1e9f)

#define CHUNK 10
#define RING  3

// s_waitcnt imm (gfx9): vmcnt[3:0]=bits3:0, expcnt=bits6:4, lgkmcnt=bits11:8,
// vmcnt[5:4]=bits15:14.
#define WAITVM(N)  __builtin_amdgcn_s_waitcnt(((N) & 15) | (7 << 4) | (15 << 8) | (((N) >> 4) << 14))
#define WAITLGKM0  __builtin_amdgcn_s_waitcnt(15 | (7 << 4) | (0 << 8) | (3 << 14))

__device__ __forceinline__ void gload_lds16(const float* g, float* l) {
    __builtin_amdgcn_global_load_lds(
        (const __attribute__((address_space(1))) void*)g,
        (__attribute__((address_space(3))) void*)l, 16, 0, 0);
}

// lane L <- lane L-1 (lane 0 <- NEG_INF), pure VALU (v_mov_b32_dpp wave_shr:1)
// — replaces __shfl_up's ds_bpermute (~120 cyc DS latency on the serial path).
__device__ __forceinline__ float dpp_shr1_neginf(float x) {
    int xi  = __builtin_bit_cast(int, x);
    int old = __builtin_bit_cast(int, NEG_INF_F);
    int r = __builtin_amdgcn_update_dpp(old, xi, 0x138, 0xF, 0xF, false);
    return __builtin_bit_cast(float, r);
}

// ======================= K1: nc14[b,x] = nc1 + nc4 =======================
__global__ __launch_bounds__(256)
void nc14_kernel(const float* __restrict__ m_p,
                 const float* __restrict__ logs_p,
                 float* __restrict__ nc14) {
    int gid = blockIdx.x * 256 + threadIdx.x;       // 0..8191  (B*TX)
    int b = gid >> 9;
    int x = gid & 511;
    const float c = -0.9189385332046727f;           // -0.5*log(2*pi)
    const float* lp = logs_p + (size_t)b * D_ * TX + x;
    const float* mp = m_p    + (size_t)b * D_ * TX + x;
    float acc1 = 0.f, acc2 = 0.f;
    for (int d = 0; d < D_; ++d) {
        float l = lp[(size_t)d * TX];
        float m = mp[(size_t)d * TX];
        float s = __expf(-2.f * l);
        acc1 += c - l;
        acc2 += m * m * s;
    }
    nc14[gid] = acc1 - 0.5f * acc2;
}

// ======================= K2: fp32 GEMM for neg_cent =======================
#define BM 128
#define BN 128
#define BK 16

__global__ __launch_bounds__(512)
void gemm_kernel(const float* __restrict__ z_p,
                 const float* __restrict__ m_p,
                 const float* __restrict__ logs_p,
                 const float* __restrict__ nc14,
                 float* __restrict__ out) {
    __shared__ float a_z [BK][BM];
    __shared__ float a_z2[BK][BM];
    __shared__ float sb_s [BK][BN];
    __shared__ float sb_ms[BK][BN];   // 32 KB total

    const int b  = blockIdx.z;
    const int m0 = blockIdx.y * BM;
    const int n0 = blockIdx.x * BN;
    const int tid = threadIdx.x;
    const int tx = tid & 31;      // 32 col-groups of 4
    const int ty = tid >> 5;      // 16 row-groups of 8

    const int skk = tid >> 5;          // staging row 0..15
    const int sy  = (tid & 31) * 4;    // staging col 0..124

    const float* zb = z_p    + (size_t)b * D_ * TY;
    const float* mb = m_p    + (size_t)b * D_ * TX;
    const float* lb = logs_p + (size_t)b * D_ * TX;

    float acc[8][4];
    #pragma unroll
    for (int i = 0; i < 8; ++i)
        #pragma unroll
        for (int j = 0; j < 4; ++j) acc[i][j] = 0.f;

    float4 va, vlg, vmm;
    auto ld = [&](int k0) {
        va  = *(const float4*)(zb + (size_t)(k0 + skk) * TY + m0 + sy);
        vlg = *(const float4*)(lb + (size_t)(k0 + skk) * TX + n0 + sy);
        vmm = *(const float4*)(mb + (size_t)(k0 + skk) * TX + n0 + sy);
    };
    auto st = [&]() {
        *(float4*)&a_z[skk][sy] = va;
        float4 w;
        w.x = -0.5f * va.x * va.x; w.y = -0.5f * va.y * va.y;
        w.z = -0.5f * va.z * va.z; w.w = -0.5f * va.w * va.w;
        *(float4*)&a_z2[skk][sy] = w;
        float4 s;
        s.x = __expf(-2.f * vlg.x); s.y = __expf(-2.f * vlg.y);
        s.z = __expf(-2.f * vlg.z); s.w = __expf(-2.f * vlg.w);
        *(float4*)&sb_s[skk][sy] = s;
        float4 ms;
        ms.x = vmm.x * s.x; ms.y = vmm.y * s.y;
        ms.z = vmm.z * s.z; ms.w = vmm.w * s.w;
        *(float4*)&sb_ms[skk][sy] = ms;
    };

    ld(0);
    for (int k0 = 0; k0 < D_; k0 += BK) {
        st();
        __syncthreads();
        if (k0 + BK < D_) ld(k0 + BK);   // prefetch next tile during compute
        #pragma unroll
        for (int kk = 0; kk < BK; ++kk) {
            float az[8], a2[8], bs[4], bm[4];
            *(float4*)&az[0] = *(const float4*)&a_z [kk][ty * 8];
            *(float4*)&az[4] = *(const float4*)&a_z [kk][ty * 8 + 4];
            *(float4*)&a2[0] = *(const float4*)&a_z2[kk][ty * 8];
            *(float4*)&a2[4] = *(const float4*)&a_z2[kk][ty * 8 + 4];
            *(float4*)&bs[0] = *(const float4*)&sb_s [kk][tx * 4];
            *(float4*)&bm[0] = *(const float4*)&sb_ms[kk][tx * 4];
            #pragma unroll
            for (int i = 0; i < 8; ++i)
                #pragma unroll
                for (int j = 0; j < 4; ++j)
                    acc[i][j] += a2[i] * bs[j] + az[i] * bm[j];
        }
        __syncthreads();
    }
    const float4 c4 = *(const float4*)(nc14 + b * TX + n0 + tx * 4);
    float* ob = out + (size_t)b * TY * TX + (size_t)m0 * TX + n0 + tx * 4;
    #pragma unroll
    for (int i = 0; i < 8; ++i) {
        float4 r;
        r.x = acc[i][0] + c4.x; r.y = acc[i][1] + c4.y;
        r.z = acc[i][2] + c4.z; r.w = acc[i][3] + c4.w;
        *(float4*)(ob + (size_t)(ty * 8 + i) * TX) = r;
    }
}

// ======================= K3: DP, single-wave async pipeline =======================
// One 64-lane wave per batch. global_load_lds (16B) prefetches chunk c+2 into a
// 3-slot LDS ring; s_waitcnt vmcnt(N) gates (queue is deterministic: 20 loads +
// 10 bit-stores per chunk). Serial-chain DS ops eliminated: DPP wave_shr for the
// forward boundary, readlane for backtrack broadcasts. Chunk ds_reads batched
// up-front so DS pipe carries throughput only.
__global__ __launch_bounds__(64, 1)
void dp_kernel(float* __restrict__ out,
               const int* __restrict__ t_xs,
               const int* __restrict__ t_ys,
               int* __restrict__ cumE) {
    const size_t PLANE = (size_t)TY * TX;
    const size_t OFF1  = (size_t)B_ * PLANE;
    const size_t OFF2  = 2 * OFF1;

    __shared__ float rows_lds[RING * CHUNK * TX];   // 60 KB
    __shared__ int   w_lds[TX];                     // 2 KB

    const int b    = blockIdx.x;
    const int lane = threadIdx.x;
    const int t_x  = t_xs[b];
    const int t_y  = t_ys[b];
    const int tym1 = t_y - 1;
    const int NC   = (t_y + CHUNK - 1) / CHUNK;

    const float* nc   = out + (size_t)b * PLANE;
    float*       attn = out + OFF1 + (size_t)b * PLANE;
    float*       logw = out + OFF2 + (size_t)b * TX;
    unsigned char* bitsb = (unsigned char*)attn;

    #pragma unroll
    for (int j = 0; j < 8; ++j) w_lds[lane * 8 + j] = 0;

    auto issue_chunk = [&](int c) {
        const int slot = c % RING;
        #pragma unroll
        for (int r = 0; r < CHUNK; ++r) {
            int y = c * CHUNK + r;
            if (y > tym1) y = tym1;
            const float* gp = nc + (size_t)y * TX + 8 * lane;   // lane-swizzled
            float* lp = rows_lds + (size_t)(slot * CHUNK + r) * TX;
            gload_lds16(gp,     lp);        // lanes land at lp + 16B*lane
            gload_lds16(gp + 4, lp + 256);
        }
    };

    // ---------------- forward ----------------
    float cum[8];
    #pragma unroll
    for (int j = 0; j < 8; ++j) cum[j] = NEG_INF_F;

    auto step = [&](int yy, float4 va, float4 vb) {
        float sh0 = dpp_shr1_neginf(cum[7]);    // VALU, no DS
        unsigned bits = (cum[0] < sh0) ? 1u : 0u;
        #pragma unroll
        for (int j = 1; j < 8; ++j)
            bits |= (cum[j] < cum[j - 1]) ? (1u << j) : 0u;
        float v[8] = {va.x, va.y, va.z, va.w, vb.x, vb.y, vb.z, vb.w};
        float c0 = v[0] + fmaxf(cum[0], sh0);
        #pragma unroll
        for (int j = 7; j >= 1; --j)          // descending: uses old cum[j-1]
            cum[j] = v[j] + fmaxf(cum[j], cum[j - 1]);
        cum[0] = c0;
        bitsb[(size_t)yy * 2048 + lane] = (unsigned char)bits;
    };

    issue_chunk(0);
    if (NC > 1) issue_chunk(1);

#define RD1(r) (*(const float4*)(base + (r) * TX + 4 * lane))
#define RD2(r) (*(const float4*)(base + (r) * TX + 256 + 4 * lane))
#define ROW(r, SA, SB)                                                      \
    do {                                                                    \
        int y = c * CHUNK + (r);                                            \
        if (y == 0) { cum[0] = (lane == 0) ? SA.x : NEG_INF_F;              \
                      bitsb[lane] = 0; /* dummy: uniform store count */ }   \
        else if (y < t_y) step(y, SA, SB);                                  \
    } while (0)

    for (int c = 0; c < NC; ++c) {
        bool full = (c + 2 < NC);
        WAITLGKM0;   // ring slot's previous ds_reads must retire before DMA refill
        if (full) issue_chunk(c + 2);
        // vmcnt queue (oldest first): L(c)20, S(c-2)10, L(c+1)20, S(c-1)10, L(c+2)20
        if (c == 0)      { WAITVM(40); }
        else if (full)   { WAITVM(50); }
        else             { WAITVM(0);  }
        __asm__ volatile("" ::: "memory");
        const float* base = rows_lds + (size_t)(c % RING) * (CHUNK * TX);
        float4 r0a = RD1(0), r0b = RD2(0);
        float4 r1a = RD1(1), r1b = RD2(1);
        float4 r2a = RD1(2), r2b = RD2(2);
        float4 r3a = RD1(3), r3b = RD2(3);
        float4 r4a = RD1(4), r4b = RD2(4);
        float4 r5a = RD1(5), r5b = RD2(5);
        float4 r6a = RD1(6), r6b = RD2(6);
        float4 r7a = RD1(7), r7b = RD2(7);
        float4 r8a = RD1(8), r8b = RD2(8);
        float4 r9a = RD1(9), r9b = RD2(9);
        ROW(0, r0a, r0b);
        ROW(1, r1a, r1b);
        ROW(2, r2a, r2b);
        ROW(3, r3a, r3b);
        ROW(4, r4a, r4b);
        ROW(5, r5a, r5b);
        ROW(6, r6a, r6b);
        ROW(7, r7a, r7b);
        ROW(8, r8a, r8b);
        ROW(9, r9a, r9b);
    }
#undef RD1
#undef RD2
#undef ROW

    // drain bit-stores before reading them back
    __builtin_amdgcn_s_waitcnt(0);
    __asm__ volatile("" ::: "memory");

    // ---------------- backtrack (durations only) ----------------
    int idx  = t_x - 1;
    int yhi  = t_y - 1;
    int ytop = t_y - 1;
    while (ytop >= 0) {
        int cnt = (ytop >= 31) ? 32 : (ytop + 1);
        int wh  = idx >> 5;
        int wlo = (wh > 0) ? wh - 1 : 0;
        unsigned vlo = 0u, vhi = 0u;
        if (lane < cnt) {
            const unsigned* rp = (const unsigned*)attn + (size_t)(ytop - lane) * TX;
            vlo = rp[wlo];
            vhi = rp[wh];
        }
        int base = wlo * 32;
        auto body = [&](int i) {
            int yy = ytop - i;
            unsigned lo = (unsigned)__builtin_amdgcn_readlane((int)vlo, i);  // uniform idx: no DS
            unsigned hi = (unsigned)__builtin_amdgcn_readlane((int)vhi, i);
            unsigned long long V = ((unsigned long long)hi << 32) | lo;
            int pos   = idx - base;
            int bit   = (int)((V >> pos) & 1ull);
            int force = (idx == yy) ? 1 : 0;
            int move  = (force | bit) & ((idx > 0) ? 1 : 0) & ((yy > 0) ? 1 : 0);
            if (move) {
                if (lane == 0) w_lds[idx] = yhi - yy + 1;
                yhi = yy - 1;
                idx -= 1;
            }
        };
        if (cnt == 32) {
            #pragma unroll
            for (int i = 0; i < 32; ++i) body(i);
        } else {
            for (int i = 0; i < cnt; ++i) body(i);
        }
        ytop -= cnt;
    }
    if (lane == 0) w_lds[idx] = yhi + 1;   // phoneme holding row 0

    // ---------------- logw + prefix-sum -> cumE ----------------
    int v[8];
    int run = 0;
    #pragma unroll
    for (int j = 0; j < 8; ++j) {
        int wv = w_lds[lane * 8 + j];
        run += wv;
        v[j] = run;                   // inclusive within lane
    }
    int off = run;
    #pragma unroll
    for (int d = 1; d < 64; d <<= 1) {
        int t = __shfl_up(off, d, 64);
        if (lane >= d) off += t;
    }
    int excl = off - run;             // exclusive across lanes
    #pragma unroll
    for (int j = 0; j < 8; ++j) {
        int x = lane * 8 + j;
        cumE[b * TX + x] = v[j] + excl;
        int wv = w_lds[x];
        logw[x] = (x < t_x) ? logf((float)wv + 1e-6f) : 0.f;
    }
}

// ======================= K4: attn one-hot fill =======================
__global__ __launch_bounds__(256)
void attn_fill_kernel(const int* __restrict__ cumE,
                      float* __restrict__ out) {
    const size_t PLANE = (size_t)TY * TX;
    const size_t OFF1  = (size_t)B_ * PLANE;
    __shared__ int cs[TX + 1];
    const int b  = blockIdx.y;
    const int y0 = blockIdx.x * 4;
    const int t  = threadIdx.x;
    if (t == 0) cs[0] = 0;
    cs[1 + t]       = cumE[b * TX + t];
    cs[1 + 256 + t] = cumE[b * TX + 256 + t];
    __syncthreads();
    const int y  = y0 + (t >> 6);
    const int x0 = (t & 63) * 8;
    float r[8];
    #pragma unroll
    for (int j = 0; j < 8; ++j)
        r[j] = (cs[x0 + j] <= y && y < cs[x0 + j + 1]) ? 1.f : 0.f;
    float* p = out + OFF1 + (size_t)b * PLANE + (size_t)y * TX + x0;
    *(float4*)p       = *(float4*)&r[0];
    *(float4*)(p + 4) = *(float4*)&r[4];
}

// ======================= launch =======================
extern "C" void kernel_launch(void* const* d_in, const int* in_sizes, int n_in,
                              void* d_out, int out_size, void* d_ws, size_t ws_size,
                              hipStream_t stream) {
    const float* z_p    = (const float*)d_in[0];
    const float* m_p    = (const float*)d_in[1];
    const float* logs_p = (const float*)d_in[2];
    const int* ph_len   = (const int*)d_in[3];
    const int* mel_len  = (const int*)d_in[4];
    float* out  = (float*)d_out;
    float* nc14 = (float*)d_ws;          // 16*512 floats = 32 KB
    int*   cumE = (int*)d_ws;            // reuses nc14's space (dead after gemm)

    nc14_kernel<<<(B_ * TX) / 256, 256, 0, stream>>>(m_p, logs_p, nc14);
    gemm_kernel<<<dim3(TX / BN, TY / BM, B_), 512, 0, stream>>>(z_p, m_p, logs_p, nc14, out);
    dp_kernel<<<B_, 64, 0, stream>>>(out, ph_len, mel_len, cumE);
    attn_fill_kernel<<<dim3(TY / 4, B_), 256, 0, stream>>>(cumE, out);
}